// Round 1
// baseline (2124.913 us; speedup 1.0000x reference)
//
#include <hip/hip_runtime.h>

#define S_LEN 2048
#define I_IN  32
#define H_DIM 64
#define O_DIM 32
#define NSEQ  256
#define NROWS (NSEQ * S_LEN)          // 524288
#define OBS_ELEMS (NROWS * O_DIM)     // 16777216
#define HID_ELEMS (NROWS * H_DIM)     // 33554432

// One wave (64 lanes) per sequence q. Lane g owns hidden unit g.
// NO barriers, NO LDS: single-wave block, h_prev broadcast via v_readlane
// (register-only, no lgkmcnt/vmcnt on the serial chain). The old version's
// __syncthreads forced s_waitcnt vmcnt(0) every step, putting the ~900cy
// HBM first-touch latency of the x prefetch on the recurrence chain
// (1755 cy/step measured). x is prefetched 3 steps deep in registers so
// its latency is fully off the chain.
__global__ __launch_bounds__(64, 1) void rnn_scan_kernel(
    const float* __restrict__ x,
    const float* __restrict__ Wih,
    const float* __restrict__ bih,
    const float* __restrict__ Whh,
    const float* __restrict__ bhh,
    float* __restrict__ hidden,
    float* __restrict__ hlast)
{
    const int q = blockIdx.x;
    const int g = threadIdx.x;

    float wih[I_IN];
#pragma unroll
    for (int i = 0; i < I_IN; ++i) wih[i] = Wih[g * I_IN + i];
    float whh[H_DIM];
#pragma unroll
    for (int h = 0; h < H_DIM; ++h) whh[h] = Whh[g * H_DIM + h];
    const float bias = bih[g] + bhh[g];

    const float4* xrow = (const float4*)(x + (size_t)q * S_LEN * I_IN); // 8 float4/step
    float* hq = hidden + (size_t)q * S_LEN * H_DIM;

    float hv = 0.0f;   // lane g's h_prev[g]; h0 = 0

    // 3-deep register prefetch pipeline (statically indexed buffers A,B,C)
    float4 A[8], B[8], C[8];
#pragma unroll
    for (int k = 0; k < 8; ++k) A[k] = xrow[0 * 8 + k];
#pragma unroll
    for (int k = 0; k < 8; ++k) B[k] = xrow[1 * 8 + k];
#pragma unroll
    for (int k = 0; k < 8; ++k) C[k] = xrow[2 * 8 + k];

    // One timestep: consume buf (x[t]), refill buf with x[tpre], update hv.
    auto step = [&](float4 (&buf)[8], const int t, const int tpre) {
        // input projection: p[g] = bias + sum_i Wih[g][i]*x[t][i]
        float p0 = bias, p1 = 0.0f, p2 = 0.0f, p3 = 0.0f;
#pragma unroll
        for (int k = 0; k < 8; ++k) {
            p0 = fmaf(wih[4 * k + 0], buf[k].x, p0);
            p1 = fmaf(wih[4 * k + 1], buf[k].y, p1);
            p2 = fmaf(wih[4 * k + 2], buf[k].z, p2);
            p3 = fmaf(wih[4 * k + 3], buf[k].w, p3);
        }

        // prefetch x[tpre] into buf (clamped; distance 3 steps ~ >1000cy)
        const int tp = (tpre < S_LEN) ? tpre : (S_LEN - 1);
#pragma unroll
        for (int k = 0; k < 8; ++k) buf[k] = xrow[tp * 8 + k];

        // recurrent matvec: z[g] = sum_h Whh[g][h] * h_prev[h]
        // h_prev[h] lives in lane h's hv -> broadcast via readlane (SGPR).
        float z0 = 0.0f, z1 = 0.0f, z2 = 0.0f, z3 = 0.0f;
#pragma unroll
        for (int h = 0; h < H_DIM; h += 4) {
            const float h0 = __int_as_float(__builtin_amdgcn_readlane(__float_as_int(hv), h + 0));
            const float h1 = __int_as_float(__builtin_amdgcn_readlane(__float_as_int(hv), h + 1));
            const float h2 = __int_as_float(__builtin_amdgcn_readlane(__float_as_int(hv), h + 2));
            const float h3 = __int_as_float(__builtin_amdgcn_readlane(__float_as_int(hv), h + 3));
            z0 = fmaf(whh[h + 0], h0, z0);
            z1 = fmaf(whh[h + 1], h1, z1);
            z2 = fmaf(whh[h + 2], h2, z2);
            z3 = fmaf(whh[h + 3], h3, z3);
        }
        const float z = ((p0 + p1) + (p2 + p3)) + ((z0 + z1) + (z2 + z3));

        // tanh(z) = 1 - 2/(exp(2z)+1): branchless, NaN-free for finite z
        const float e = __expf(2.0f * z);
        hv = 1.0f - 2.0f / (e + 1.0f);

        hq[t * H_DIM + g] = hv;   // store: never waited on (no barrier)
    };

    // 2046 = 3*682 main steps, then 2 tail steps (prefetch clamped/wasted)
    for (int t = 0; t < 2046; t += 3) {
        step(A, t + 0, t + 3);
        step(B, t + 1, t + 4);
        step(C, t + 2, t + 5);
    }
    step(A, 2046, S_LEN - 1);
    step(B, 2047, S_LEN - 1);

    hlast[q * H_DIM + g] = hv;
}

// obs[row][o] = sum_h hidden[row][h]*W_fc[o][h] + b_fc[o]
// 4096 blocks x 256 threads; 128 rows/block. h tile staged TRANSPOSED in LDS
// (hsh[h][r], row stride 132 keeps 16B alignment), W^T staged as wt[h][o].
// Thread (og,rg) computes 4 rows x 4 outs; inner loop = 2 ds_read_b128 + 16 fma.
__global__ __launch_bounds__(256) void obs_kernel(
    const float* __restrict__ hidden,
    const float* __restrict__ Wfc,
    const float* __restrict__ bfc,
    float* __restrict__ obs)
{
    __shared__ float hsh[H_DIM][132];   // [h][row], 33 KB
    __shared__ float wt[H_DIM][36];     // [h][o],   9 KB
    __shared__ float bsh[O_DIM];

    const int tid = threadIdx.x;
    const size_t rowbase = (size_t)blockIdx.x * 128;

    // stage hidden tile transposed: 2048 float4 loads (8 per thread), coalesced
    const float4* hg = (const float4*)(hidden + rowbase * H_DIM);
#pragma unroll
    for (int s = 0; s < 8; ++s) {
        const int f = tid + 256 * s;     // 0..2047; 16 float4 per row, 128 rows
        const int r = f >> 4, h4 = f & 15;
        const float4 v = hg[f];
        hsh[h4 * 4 + 0][r] = v.x;
        hsh[h4 * 4 + 1][r] = v.y;
        hsh[h4 * 4 + 2][r] = v.z;
        hsh[h4 * 4 + 3][r] = v.w;
    }
    // stage W^T (2048 elems) and bias
#pragma unroll
    for (int s = 0; s < 8; ++s) {
        const int e = tid + 256 * s;     // e = o*64 + h
        wt[e & 63][e >> 6] = Wfc[e];
    }
    if (tid < O_DIM) bsh[tid] = bfc[tid];
    __syncthreads();

    const int rg = tid & 31, og = tid >> 5;
    const int r0 = rg * 4, o0 = og * 4;

    float acc[4][4];
#pragma unroll
    for (int j = 0; j < 4; ++j)
#pragma unroll
        for (int i = 0; i < 4; ++i) acc[j][i] = 0.0f;

#pragma unroll 8
    for (int h = 0; h < H_DIM; ++h) {
        const float4 hv = *(const float4*)&hsh[h][r0];  // rows r0..r0+3
        const float4 wv = *(const float4*)&wt[h][o0];   // outs o0..o0+3 (broadcast)
        const float hj[4] = {hv.x, hv.y, hv.z, hv.w};
        const float wi[4] = {wv.x, wv.y, wv.z, wv.w};
#pragma unroll
        for (int j = 0; j < 4; ++j)
#pragma unroll
            for (int i = 0; i < 4; ++i)
                acc[j][i] = fmaf(hj[j], wi[i], acc[j][i]);
    }

    const float4 bv = *(const float4*)&bsh[o0];
    const float bi[4] = {bv.x, bv.y, bv.z, bv.w};
#pragma unroll
    for (int j = 0; j < 4; ++j) {
        float4 ov;
        ov.x = acc[j][0] + bi[0];
        ov.y = acc[j][1] + bi[1];
        ov.z = acc[j][2] + bi[2];
        ov.w = acc[j][3] + bi[3];
        *(float4*)&obs[(rowbase + r0 + j) * O_DIM + o0] = ov;
    }
}

extern "C" void kernel_launch(void* const* d_in, const int* in_sizes, int n_in,
                              void* d_out, int out_size, void* d_ws, size_t ws_size,
                              hipStream_t stream)
{
    const float* x   = (const float*)d_in[0];
    const float* Wih = (const float*)d_in[1];
    const float* bih = (const float*)d_in[2];
    const float* Whh = (const float*)d_in[3];
    const float* bhh = (const float*)d_in[4];
    const float* Wfc = (const float*)d_in[5];
    const float* bfc = (const float*)d_in[6];

    float* out    = (float*)d_out;
    float* obs    = out;                         // [8,32,2048,32]
    float* hidden = out + (size_t)OBS_ELEMS;     // [8,32,2048,64]
    float* hlast  = hidden + (size_t)HID_ELEMS;  // [8,32,64]

    rnn_scan_kernel<<<NSEQ, 64, 0, stream>>>(x, Wih, bih, Whh, bhh, hidden, hlast);
    obs_kernel<<<NROWS / 128, 256, 0, stream>>>(hidden, Wfc, bfc, obs);
}

// Round 2
// 801.754 us; speedup vs baseline: 2.6503x; 2.6503x over previous
//
#include <hip/hip_runtime.h>

#define S_LEN 2048
#define I_IN  32
#define H_DIM 64
#define O_DIM 32
#define NSEQ  256
#define NROWS (NSEQ * S_LEN)          // 524288
#define OBS_ELEMS (NROWS * O_DIM)     // 16777216
#define HID_ELEMS (NROWS * H_DIM)     // 33554432

// ---------------------------------------------------------------------------
// Kernel 1: pre[row][g] = bih[g]+bhh[g] + sum_i x[row][i]*Wih[g][i]
// Row-per-thread (half of the 64 outputs each); W_ih staged in LDS and read
// with WAVE-UNIFORM addresses -> broadcast, conflict-free. Output written
// into the `hidden` buffer (same shape/size as pre); the scan kernel
// consumes pre[t] 8 steps before it overwrites hidden[t], so aliasing is
// race-free.
// ---------------------------------------------------------------------------
__global__ __launch_bounds__(256) void pre_kernel(
    const float* __restrict__ x,
    const float* __restrict__ Wih,
    const float* __restrict__ bih,
    const float* __restrict__ bhh,
    float* __restrict__ pre)
{
    __shared__ float ws[I_IN][68];   // [i][g], stride 68 keeps 16B align + spreads banks
    __shared__ float bsh[H_DIM];

    const int tid = threadIdx.x;
#pragma unroll
    for (int s = 0; s < 8; ++s) {
        const int e = tid + 256 * s;          // e = g*32 + i
        ws[e & 31][e >> 5] = Wih[e];
    }
    if (tid < H_DIM) bsh[tid] = bih[tid] + bhh[tid];
    __syncthreads();

    const int r    = tid & 127;
    const int half = tid >> 7;                // wave-uniform (waves 0,1 -> 0; 2,3 -> 1)
    const size_t row = (size_t)blockIdx.x * 128 + r;
    const int o0 = half * 32;

    // own x row in registers: 32 floats, coalesced-ish float4 loads
    float4 xr[8];
    const float4* xg = (const float4*)(x + row * I_IN);
#pragma unroll
    for (int k = 0; k < 8; ++k) xr[k] = xg[k];

    float4 acc[8];
#pragma unroll
    for (int j = 0; j < 8; ++j) acc[j] = *(const float4*)&bsh[o0 + 4 * j];

#pragma unroll
    for (int k = 0; k < 8; ++k) {
        const float xi0 = xr[k].x, xi1 = xr[k].y, xi2 = xr[k].z, xi3 = xr[k].w;
#pragma unroll
        for (int j = 0; j < 8; ++j) {
            const float4 w0 = *(const float4*)&ws[4 * k + 0][o0 + 4 * j];
            const float4 w1 = *(const float4*)&ws[4 * k + 1][o0 + 4 * j];
            const float4 w2 = *(const float4*)&ws[4 * k + 2][o0 + 4 * j];
            const float4 w3 = *(const float4*)&ws[4 * k + 3][o0 + 4 * j];
            acc[j].x = fmaf(xi0, w0.x, acc[j].x);
            acc[j].y = fmaf(xi0, w0.y, acc[j].y);
            acc[j].z = fmaf(xi0, w0.z, acc[j].z);
            acc[j].w = fmaf(xi0, w0.w, acc[j].w);
            acc[j].x = fmaf(xi1, w1.x, acc[j].x);
            acc[j].y = fmaf(xi1, w1.y, acc[j].y);
            acc[j].z = fmaf(xi1, w1.z, acc[j].z);
            acc[j].w = fmaf(xi1, w1.w, acc[j].w);
            acc[j].x = fmaf(xi2, w2.x, acc[j].x);
            acc[j].y = fmaf(xi2, w2.y, acc[j].y);
            acc[j].z = fmaf(xi2, w2.z, acc[j].z);
            acc[j].w = fmaf(xi2, w2.w, acc[j].w);
            acc[j].x = fmaf(xi3, w3.x, acc[j].x);
            acc[j].y = fmaf(xi3, w3.y, acc[j].y);
            acc[j].z = fmaf(xi3, w3.z, acc[j].z);
            acc[j].w = fmaf(xi3, w3.w, acc[j].w);
        }
    }

    float4* pr = (float4*)(pre + row * H_DIM + o0);
#pragma unroll
    for (int j = 0; j < 8; ++j) pr[j] = acc[j];
}

// ---------------------------------------------------------------------------
// Kernel 2: the serial scan. One wave per sequence; lane g owns h[g].
// Per-step state is SCALARS ONLY (whh[64] + 8-deep pre prefetch + hv ~ 90
// VGPRs) so the allocator cannot pull the R1 trick of dropping buffers and
// sinking loads onto the chain. No LDS, no barriers; h broadcast via
// v_readlane (register->SGPR, nothing enters vmcnt/lgkmcnt on the chain).
// `hidden` holds pre on entry (written by pre_kernel) and is overwritten
// in place: pre[t] is read (prefetched) 8 steps before hidden[t] is stored.
// ---------------------------------------------------------------------------
__device__ __forceinline__ float rl(float v, int l)
{
    return __int_as_float(__builtin_amdgcn_readlane(__float_as_int(v), l));
}

__device__ __forceinline__ float rnn_step(float pv, float hv, const float* whh)
{
    float z0 = pv, z1 = 0.0f, z2 = 0.0f, z3 = 0.0f;
    float z4 = 0.0f, z5 = 0.0f, z6 = 0.0f, z7 = 0.0f;
#pragma unroll
    for (int h = 0; h < H_DIM; h += 8) {
        z0 = fmaf(whh[h + 0], rl(hv, h + 0), z0);
        z1 = fmaf(whh[h + 1], rl(hv, h + 1), z1);
        z2 = fmaf(whh[h + 2], rl(hv, h + 2), z2);
        z3 = fmaf(whh[h + 3], rl(hv, h + 3), z3);
        z4 = fmaf(whh[h + 4], rl(hv, h + 4), z4);
        z5 = fmaf(whh[h + 5], rl(hv, h + 5), z5);
        z6 = fmaf(whh[h + 6], rl(hv, h + 6), z6);
        z7 = fmaf(whh[h + 7], rl(hv, h + 7), z7);
    }
    const float z = ((z0 + z1) + (z2 + z3)) + ((z4 + z5) + (z6 + z7));
    // tanh(z) = 1 - 2/(exp(2z)+1): branchless, NaN-free for finite z
    const float e = __expf(2.0f * z);
    return fmaf(-2.0f, __builtin_amdgcn_rcpf(e + 1.0f), 1.0f);
}

__global__ __launch_bounds__(64, 1) void rnn_scan_kernel(
    const float* __restrict__ Whh,
    float* __restrict__ hidden,   // contains pre on entry; h written in place
    float* __restrict__ hlast)
{
    const int q = blockIdx.x;
    const int g = threadIdx.x;

    float whh[H_DIM];
#pragma unroll
    for (int h = 0; h < H_DIM; ++h) whh[h] = Whh[g * H_DIM + h];

    float* hq = hidden + (size_t)q * S_LEN * H_DIM;

    float hv = 0.0f;
    float buf[8];
#pragma unroll
    for (int j = 0; j < 8; ++j) buf[j] = hq[j * H_DIM + g];

    for (int tb = 0; tb < S_LEN - 8; tb += 8) {
        float nbuf[8];
        // issue next macro-block's loads first: ~8 steps (>2000cy) of cover
#pragma unroll
        for (int j = 0; j < 8; ++j) nbuf[j] = hq[(tb + 8 + j) * H_DIM + g];
#pragma unroll
        for (int j = 0; j < 8; ++j) {
            hv = rnn_step(buf[j], hv, whh);
            hq[(tb + j) * H_DIM + g] = hv;
        }
#pragma unroll
        for (int j = 0; j < 8; ++j) buf[j] = nbuf[j];
    }
    // tail macro-block: no prefetch
#pragma unroll
    for (int j = 0; j < 8; ++j) {
        hv = rnn_step(buf[j], hv, whh);
        hq[(S_LEN - 8 + j) * H_DIM + g] = hv;
    }

    hlast[q * H_DIM + g] = hv;
}

// ---------------------------------------------------------------------------
// Kernel 3: obs[row][o] = sum_h hidden[row][h]*W_fc[o][h] + b_fc[o]
// Row-per-thread (half of the 32 outputs each); hidden row lives in 64
// VGPRs, W_fc^T read from LDS with WAVE-UNIFORM addresses (broadcast,
// conflict-free). The old 4x4-register-tile version moved ~16 MB/CU
// through the LDS pipe (222 us); this one is HBM-bound.
// ---------------------------------------------------------------------------
__global__ __launch_bounds__(256) void obs_kernel(
    const float* __restrict__ hidden,
    const float* __restrict__ Wfc,
    const float* __restrict__ bfc,
    float* __restrict__ obs)
{
    __shared__ float wt[H_DIM][36];   // [h][o], stride 36 keeps 16B align
    __shared__ float bsh[O_DIM];

    const int tid = threadIdx.x;
#pragma unroll
    for (int s = 0; s < 8; ++s) {
        const int e = tid + 256 * s;          // e = o*64 + h
        wt[e & 63][e >> 6] = Wfc[e];
    }
    if (tid < O_DIM) bsh[tid] = bfc[tid];
    __syncthreads();

    const int r    = tid & 127;
    const int half = tid >> 7;                // wave-uniform
    const size_t row = (size_t)blockIdx.x * 128 + r;
    const int o0 = half * 16;

    float4 hr[16];
    const float4* hg = (const float4*)(hidden + row * H_DIM);
#pragma unroll
    for (int k = 0; k < 16; ++k) hr[k] = hg[k];

    float4 acc[4];
#pragma unroll
    for (int j = 0; j < 4; ++j) acc[j] = *(const float4*)&bsh[o0 + 4 * j];

#pragma unroll
    for (int k = 0; k < 16; ++k) {
        const float h0 = hr[k].x, h1 = hr[k].y, h2 = hr[k].z, h3 = hr[k].w;
#pragma unroll
        for (int j = 0; j < 4; ++j) {
            const float4 w0 = *(const float4*)&wt[4 * k + 0][o0 + 4 * j];
            const float4 w1 = *(const float4*)&wt[4 * k + 1][o0 + 4 * j];
            const float4 w2 = *(const float4*)&wt[4 * k + 2][o0 + 4 * j];
            const float4 w3 = *(const float4*)&wt[4 * k + 3][o0 + 4 * j];
            acc[j].x = fmaf(h0, w0.x, acc[j].x);
            acc[j].y = fmaf(h0, w0.y, acc[j].y);
            acc[j].z = fmaf(h0, w0.z, acc[j].z);
            acc[j].w = fmaf(h0, w0.w, acc[j].w);
            acc[j].x = fmaf(h1, w1.x, acc[j].x);
            acc[j].y = fmaf(h1, w1.y, acc[j].y);
            acc[j].z = fmaf(h1, w1.z, acc[j].z);
            acc[j].w = fmaf(h1, w1.w, acc[j].w);
            acc[j].x = fmaf(h2, w2.x, acc[j].x);
            acc[j].y = fmaf(h2, w2.y, acc[j].y);
            acc[j].z = fmaf(h2, w2.z, acc[j].z);
            acc[j].w = fmaf(h2, w2.w, acc[j].w);
            acc[j].x = fmaf(h3, w3.x, acc[j].x);
            acc[j].y = fmaf(h3, w3.y, acc[j].y);
            acc[j].z = fmaf(h3, w3.z, acc[j].z);
            acc[j].w = fmaf(h3, w3.w, acc[j].w);
        }
    }

    float4* op = (float4*)(obs + row * O_DIM + o0);
#pragma unroll
    for (int j = 0; j < 4; ++j) op[j] = acc[j];
}

extern "C" void kernel_launch(void* const* d_in, const int* in_sizes, int n_in,
                              void* d_out, int out_size, void* d_ws, size_t ws_size,
                              hipStream_t stream)
{
    const float* x   = (const float*)d_in[0];
    const float* Wih = (const float*)d_in[1];
    const float* bih = (const float*)d_in[2];
    const float* Whh = (const float*)d_in[3];
    const float* bhh = (const float*)d_in[4];
    const float* Wfc = (const float*)d_in[5];
    const float* bfc = (const float*)d_in[6];

    float* out    = (float*)d_out;
    float* obs    = out;                         // [8,32,2048,32]
    float* hidden = out + (size_t)OBS_ELEMS;     // [8,32,2048,64]
    float* hlast  = hidden + (size_t)HID_ELEMS;  // [8,32,64]

    // pre is materialized IN the hidden buffer (same shape), then the scan
    // overwrites it in place (reads run 8 steps ahead of writes).
    pre_kernel<<<NROWS / 128, 256, 0, stream>>>(x, Wih, bih, bhh, hidden);
    rnn_scan_kernel<<<NSEQ, 64, 0, stream>>>(Whh, hidden, hlast);
    obs_kernel<<<NROWS / 128, 256, 0, stream>>>(hidden, Wfc, bfc, obs);
}